// Round 7
// baseline (365.156 us; speedup 1.0000x reference)
//
#include <hip/hip_runtime.h>
#include <math.h>

#define LEN   5440
#define NB    2
#define MROWS (NB * LEN)   // 10880
#define DM    256
#define NH    8
#define HD    32
#define NLV   4
#define NPT   4
#define DFFN  1024

typedef __attribute__((ext_vector_type(8))) short bf16x8;
typedef __attribute__((ext_vector_type(4))) short bf16x4;
typedef __attribute__((ext_vector_type(4))) float f32x4;

#define MFMA16 __builtin_amdgcn_mfma_f32_16x16x32_bf16

__device__ __forceinline__ short f2bf(float f) {
    union { float f; unsigned u; } cv; cv.f = f;
    unsigned r = cv.u + 0x7fffu + ((cv.u >> 16) & 1u);   // RNE
    return (short)(r >> 16);
}
__device__ __forceinline__ float bf2f(short s) {
    union { unsigned u; float f; } cv;
    cv.u = ((unsigned)(unsigned short)s) << 16;
    return cv.f;
}

__device__ __forceinline__ void gload16(const short* g, short* l) {
    __builtin_amdgcn_global_load_lds(
        (__attribute__((address_space(1))) void*)g,
        (__attribute__((address_space(3))) void*)l, 16, 0, 0);
}

template <int N> __device__ __forceinline__ void vmwait();
template <> __device__ __forceinline__ void vmwait<0>() { asm volatile("s_waitcnt vmcnt(0)" ::: "memory"); }
template <> __device__ __forceinline__ void vmwait<9>() { asm volatile("s_waitcnt vmcnt(9)" ::: "memory"); }

// BK=64 rows are 128B = 8 x 16B chunks; phys_chunk = logical_chunk ^ (row&7).
// Involution applied on BOTH the staging source and the ds_read address.

// ---------------------------------------------------------------------------
// Merged one-shot prep (unchanged).
// ---------------------------------------------------------------------------
__global__ __launch_bounds__(256) void prep_all(
    const float* __restrict__ Wv,  const float* __restrict__ Woff,
    const float* __restrict__ Wa,  const float* __restrict__ Wo,
    const float* __restrict__ Wl1, const float* __restrict__ Wl2,
    short* __restrict__ out,
    const float4* __restrict__ s4, const float4* __restrict__ p4,
    bf16x4* __restrict__ curb, bf16x4* __restrict__ qb)
{
    __shared__ short T[32][33];
    if (blockIdx.x >= 1472) {
        const int i = (blockIdx.x - 1472) * 256 + threadIdx.x;
        float4 s = s4[i], p = p4[i];
        bf16x4 c, q;
        c[0] = f2bf(s.x); c[1] = f2bf(s.y); c[2] = f2bf(s.z); c[3] = f2bf(s.w);
        q[0] = f2bf(s.x + p.x); q[1] = f2bf(s.y + p.y);
        q[2] = f2bf(s.z + p.z); q[3] = f2bf(s.w + p.w);
        curb[i] = c; qb[i] = q;
        return;
    }
    int bx = blockIdx.x;
    int l  = bx / 736;
    int t  = bx % 736;
    const float* src; int K, N; long doff;
    if      (t < 64)  { src = Wv;   K = 256;  N = 256;  doff = 0;      }
    else if (t < 128) { src = Woff; K = 256;  N = 256;  doff = 65536;  t -= 64;  }
    else if (t < 160) { src = Wa;   K = 256;  N = 128;  doff = 131072; t -= 128; }
    else if (t < 224) { src = Wo;   K = 256;  N = 256;  doff = 163840; t -= 160; }
    else if (t < 480) { src = Wl1;  K = 256;  N = 1024; doff = 229376; t -= 224; }
    else              { src = Wl2;  K = 1024; N = 256;  doff = 491520; t -= 480; }
    src += (long)l * K * N;
    short* dst = out + (long)l * 753664 + doff;

    const int ntx = N / 32;
    const int n0 = (t % ntx) * 32, k0 = (t / ntx) * 32;

    const int tid = threadIdx.x;
    {
        const int n = tid & 31, kq = tid >> 5;
        #pragma unroll
        for (int i = 0; i < 4; ++i) {
            int k = kq * 4 + i;
            T[n][k] = f2bf(src[(long)(k0 + k) * N + n0 + n]);
        }
    }
    __syncthreads();
    {
        const int k = tid & 31, nq = tid >> 5;
        #pragma unroll
        for (int i = 0; i < 4; ++i) {
            int n = nq * 4 + i;
            dst[(long)(n0 + n) * K + k0 + k] = T[n][k];
        }
    }
}

// ---------------------------------------------------------------------------
// B-panel-resident GEMM core: block stages weight panel (128 rows x KLEN)
// into LDS ONCE (KLEN/64 slabs of [128 rows][64 shorts], XOR-swizzled), then
// grid-strides over M128 tiles. A is loaded DIRECTLY into registers in MFMA
// fragment layout (16B/lane, 64B-line coalesced per instruction). The M/K
// loops have ZERO barriers and zero re-staging: minimum weight traffic,
// compiler-scheduled load pipelining.
// OMODE: 0 f32 row-major (+optional bias), 1 bf16 (+RELU), 2 bf16 V-planes.
// ---------------------------------------------------------------------------
template <int RELU, int OMODE, int KLEN>
__device__ __forceinline__ void panel_core(
    short* panel, const short* __restrict__ A, int astr,
    const short* __restrict__ W, int wstr,
    const float* __restrict__ bias, float* __restrict__ Cf,
    short* __restrict__ Cb, int ldc, int ccol0, int nMt)
{
    constexpr int NSLAB = KLEN / 64;
    const int t    = threadIdx.x;
    const int wave = t >> 6, lane = t & 63;
    const int wm   = (wave & 1) * 64;
    const int wn   = (wave >> 1) * 64;
    const int lm   = lane & 15;
    const int chkg = lane >> 4;

    // ---- one-shot panel load: slab s, rows ro..ro+31 per issue ----
    {
        const int prow = t >> 3;          // 0..31 within issue
        const int pc   = t & 7;
        #pragma unroll
        for (int s = 0; s < NSLAB; ++s)
            #pragma unroll
            for (int ro = 0; ro < 128; ro += 32) {
                const int row = ro + prow;
                gload16(W + (long)row * wstr + s * 64 + ((pc ^ (row & 7)) * 8),
                        panel + s * 8192 + ro * 64 + (wave & 3) * 0
                              + ( (t >> 6) * 512 ) );
            }
    }
    vmwait<0>();
    __syncthreads();

    int offB[4];
    #pragma unroll
    for (int u = 0; u < 4; ++u) {
        const int r = wn + u * 16 + lm;
        offB[u] = r * 64 + ((chkg ^ (r & 7)) * 8);
    }

    const int col = lane & 15;
    const int rq  = (lane >> 4) * 4;

    for (int mt = blockIdx.y; mt < nMt; mt += (int)gridDim.y) {
        const int m0 = mt * 128;
        f32x4 acc[4][4] = {};
        #pragma unroll
        for (int kt = 0; kt < NSLAB; ++kt) {
            bf16x8 a0[4], a1[4], b0[4], b1[4];
            #pragma unroll
            for (int s = 0; s < 4; ++s) {
                const short* ap = A + (long)(m0 + wm + s * 16 + lm) * astr
                                    + kt * 64 + chkg * 8;
                a0[s] = *(const bf16x8*)ap;
                a1[s] = *(const bf16x8*)(ap + 32);
            }
            #pragma unroll
            for (int u = 0; u < 4; ++u) {
                b0[u] = *(const bf16x8*)(panel + kt * 8192 + offB[u]);
                b1[u] = *(const bf16x8*)(panel + kt * 8192 + (offB[u] ^ 32));
            }
            #pragma unroll
            for (int s = 0; s < 4; ++s)
                #pragma unroll
                for (int u = 0; u < 4; ++u) {
                    acc[s][u] = MFMA16(a0[s], b0[u], acc[s][u], 0, 0, 0);
                    acc[s][u] = MFMA16(a1[s], b1[u], acc[s][u], 0, 0, 0);
                }
        }

        #pragma unroll
        for (int s = 0; s < 4; ++s) {
            #pragma unroll
            for (int u = 0; u < 4; ++u) {
                const int gn = ccol0 + wn + u * 16 + col;
                const float bb = bias ? bias[gn] : 0.f;
                #pragma unroll
                for (int r = 0; r < 4; ++r) {
                    const int gm = m0 + wm + s * 16 + rq + r;
                    float v = acc[s][u][r] + bb;
                    if (RELU) v = fmaxf(v, 0.f);
                    if (OMODE == 0) {
                        Cf[(long)gm * ldc + gn] = v;
                    } else if (OMODE == 1) {
                        Cb[(long)gm * ldc + gn] = f2bf(v);
                    } else {
                        const int n   = gm / LEN;
                        const int pix = gm - n * LEN;
                        const int h   = gn >> 5, d = gn & 31;
                        Cb[((long)(n * NH + h) * LEN + pix) * 32 + d] = f2bf(v);
                    }
                }
            }
        }
    }
}

// qkv: 5 weight panels of 128 rows over [Wv|Woff|Wa] (640 rows, K=256).
__global__ __launch_bounds__(256) void qkv_panel(
    const short* __restrict__ curb, const short* __restrict__ qb,
    const short* __restrict__ Wt, const float* __restrict__ bv,
    const float* __restrict__ boff, const float* __restrict__ ba,
    short* __restrict__ Vb, float* __restrict__ OFF, float* __restrict__ AW)
{
    __shared__ __align__(16) short panel[4 * 8192];   // 64KB
    const int nc = blockIdx.x;                        // 0..4
    const short* W = Wt + (long)nc * 128 * 256;
    if (nc < 2) {
        panel_core<0, 2, 256>(panel, curb, 256, W, 256, bv, (float*)nullptr,
                              Vb, 256, nc * 128, 85);
    } else if (nc < 4) {
        panel_core<0, 0, 256>(panel, qb, 256, W, 256, boff, OFF,
                              (short*)nullptr, 256, (nc - 2) * 128, 85);
    } else {
        panel_core<0, 0, 256>(panel, qb, 256, W, 256, ba, AW,
                              (short*)nullptr, 128, 0, 85);
    }
}

// ffn1: 8 panels of 128 rows of Wl1t (1024 rows, K=256); out bf16 + relu.
__global__ __launch_bounds__(256) void ffn1_panel(
    const short* __restrict__ XAb, const short* __restrict__ W0,
    const float* __restrict__ bias, short* __restrict__ FFNb)
{
    __shared__ __align__(16) short panel[4 * 8192];   // 64KB
    const int nc = blockIdx.x;                        // 0..7
    panel_core<1, 1, 256>(panel, XAb, 256, W0 + (long)nc * 128 * 256, 256,
                          bias, (float*)nullptr, FFNb, 1024, nc * 128, 85);
}

// ln2 split-K partials: grid.x = 4 -> (kk = x>>1, nc = x&1). Panel = 128 rows
// of Wl2t, K-half 512 (8 slabs, 128KB LDS). PART[kk] f32, no bias.
__global__ __launch_bounds__(256) void ln2_panel(
    const short* __restrict__ FFNb, const short* __restrict__ W0,
    float* __restrict__ PART)
{
    __shared__ __align__(16) short panel[8 * 8192];   // 128KB
    const int kk = blockIdx.x >> 1, nc = blockIdx.x & 1;
    panel_core<0, 0, 512>(panel, FFNb + kk * 512, 1024,
                          W0 + (long)nc * 128 * 1024 + kk * 512, 1024,
                          (const float*)nullptr, PART + (long)kk * MROWS * DM,
                          (short*)nullptr, 256, nc * 128, 85);
}

// ---------------------------------------------------------------------------
// Fused GEMM + residual(bf16) + LayerNorm, M32 tile, N=256, BK=64 (R6).
// ---------------------------------------------------------------------------
template <int K>
__global__ __launch_bounds__(256) void gemm_ln(
    const short* __restrict__ A, const short* __restrict__ Wt,
    const float* __restrict__ bias, const short* __restrict__ residb,
    const float* __restrict__ g, const float* __restrict__ be,
    short* __restrict__ outb, short* __restrict__ outq,
    float* __restrict__ outf, const float* __restrict__ pos)
{
    constexpr int NT = K / 64;
    static_assert(NT >= 4 && (NT & 1) == 0, "NT even >= 4");
    __shared__ __align__(16) short As[2 * 32 * 64];    // 2 x 2048
    __shared__ __align__(16) short Bs[2 * 256 * 64];   // 2 x 16384
    __shared__ float red[2][32][2];

    const int t    = threadIdx.x;
    const int wave = t >> 6, lane = t & 63;
    const int wm   = (wave & 1) * 16;
    const int wn   = (wave >> 1) * 128;
    const int lm   = lane & 15;
    const int chkg = lane >> 4;
    const int rq   = chkg * 4;
    const int m0   = blockIdx.x * 32;

    // resid prefetch FIRST (oldest vmcnt events)
    short rr[8][4];
    #pragma unroll
    for (int u = 0; u < 8; ++u)
        #pragma unroll
        for (int r = 0; r < 4; ++r)
            rr[u][r] = residb[(long)(m0 + wm + rq + r) * DM + wn + u * 16 + lm];
    asm volatile("" ::: "memory");

    // staging: A = 1 issue (block-wide 32 rows x 8 chunks), B = 8 issues
    const int arow = t >> 3;
    const short* aSp = A + (long)(m0 + arow) * K + (((t & 7) ^ (arow & 7)) * 8);
    const int aDst = wave * 512;
    const short* bSp[8]; int bDst[8];
    #pragma unroll
    for (int j = 0; j < 8; ++j) {
        const int row = wave * 64 + j * 8 + (lane >> 3);
        const int sc  = (lane & 7) ^ (row & 7);
        bSp[j] = Wt + (long)row * K + sc * 8;
        bDst[j] = wave * 4096 + j * 512;
    }

    const int offA = (wm + lm) * 64 + ((chkg ^ ((wm + lm) & 7)) * 8);
    int offB[8];
    #pragma unroll
    for (int u = 0; u < 8; ++u) {
        const int r = wn + u * 16 + lm;
        offB[u] = r * 64 + ((chkg ^ (r & 7)) * 8);
    }

    f32x4 acc[8] = {};

#define STGL(BUF, KT) do {                                            \
        const int _ko = (KT) * 64;                                    \
        gload16(aSp + _ko, As + (BUF) * 2048 + aDst);                 \
        _Pragma("unroll")                                             \
        for (int j = 0; j < 8; ++j)                                   \
            gload16(bSp[j] + _ko, Bs + (BUF) * 16384 + bDst[j]);      \
    } while (0)

#define GBLN(T, BUF, WN, DOSTAGE) do {                                \
        vmwait<WN>();                                                 \
        __builtin_amdgcn_s_barrier();                                 \
        bf16x8 af0 = *(const bf16x8*)(As + (BUF) * 2048 + offA);      \
        bf16x8 af1 = *(const bf16x8*)(As + (BUF) * 2048 + (offA ^ 32)); \
        bf16x8 b0[8], b1[8];                                          \
        _Pragma("unroll")                                             \
        for (int u = 0; u < 8; ++u) {                                 \
            b0[u] = *(const bf16x8*)(Bs + (BUF) * 16384 + offB[u]);   \
            b1[u] = *(const bf16x8*)(Bs + (BUF) * 16384 + (offB[u] ^ 32)); \
        }                                                             \
        asm volatile("s_waitcnt lgkmcnt(0)" ::: "memory");            \
        __builtin_amdgcn_s_barrier();                                 \
        __builtin_amdgcn_sched_barrier(0);                            \
        if (DOSTAGE) STGL(BUF, (T) + 2);                              \
        _Pragma("unroll")                                             \
        for (int u = 0; u < 8; ++u) {                                 \
            acc[u] = MFMA16(af0, b0[u], acc[u], 0, 0, 0);             \
            acc[u] = MFMA16(af1, b1[u], acc[u], 0, 0, 0);             \
        }                                                             \
    } while (0)

    STGL(0, 0);
    STGL(1, 1);
    for (int tt = 0; tt < NT - 2; tt += 2) {
        GBLN(tt,     0, 9, true);
        GBLN(tt + 1, 1, 9, true);
    }
    GBLN(NT - 2, 0, 9, false);
    GBLN(NT - 1, 1, 0, false);
#undef GBLN
#undef STGL

    #pragma unroll
    for (int u = 0; u < 8; ++u) {
        const int gn = wn + u * 16 + lm;
        const float bb = bias[gn];
        #pragma unroll
        for (int r = 0; r < 4; ++r)
            acc[u][r] += bb + bf2f(rr[u][r]);
    }

    float rs[4], r2[4];
    #pragma unroll
    for (int r = 0; r < 4; ++r) {
        float s = 0.f, s2 = 0.f;
        #pragma unroll
        for (int u = 0; u < 8; ++u) { const float v = acc[u][r]; s += v; s2 += v * v; }
        rs[r] = s; r2[r] = s2;
    }
    #pragma unroll
    for (int o = 1; o < 16; o <<= 1)
        #pragma unroll
        for (int r = 0; r < 4; ++r) {
            rs[r] += __shfl_xor(rs[r], o, 64);
            r2[r] += __shfl_xor(r2[r], o, 64);
        }
    if (lm == 0) {
        #pragma unroll
        for (int r = 0; r < 4; ++r) {
            red[wave >> 1][wm + rq + r][0] = rs[r];
            red[wave >> 1][wm + rq + r][1] = r2[r];
        }
    }
    __syncthreads();
    #pragma unroll
    for (int r = 0; r < 4; ++r) {
        const int row = wm + rq + r;
        const float ts = red[0][row][0] + red[1][row][0];
        const float t2 = red[0][row][1] + red[1][row][1];
        const float mean = ts * (1.f / DM);
        const float var  = t2 * (1.f / DM) - mean * mean;
        rs[r] = mean;
        r2[r] = rsqrtf(var + 1e-5f);
    }
    #pragma unroll
    for (int u = 0; u < 8; ++u) {
        const int gn = wn + u * 16 + lm;
        const float gg = g[gn], bbe = be[gn];
        #pragma unroll
        for (int r = 0; r < 4; ++r) {
            const long gm = m0 + wm + rq + r;
            const float o = (acc[u][r] - rs[r]) * r2[r] * gg + bbe;
            if (outb) outb[gm * DM + gn] = f2bf(o);
            if (outq) outq[gm * DM + gn] = f2bf(o + pos[gm * DM + gn]);
            if (outf) outf[gm * DM + gn] = o;
        }
    }
}

// ---------------------------------------------------------------------------
// Split-K ln2 finisher (unchanged).
// ---------------------------------------------------------------------------
__global__ __launch_bounds__(256) void ln2_fin_k(
    const float* __restrict__ PART, const short* __restrict__ residb,
    const float* __restrict__ bl2, const float* __restrict__ g,
    const float* __restrict__ be, short* __restrict__ outb,
    short* __restrict__ outq, float* __restrict__ outf,
    const float* __restrict__ pos)
{
    const int wave = threadIdx.x >> 6, lane = threadIdx.x & 63;
    const int c0 = lane * 4;
    const f32x4 bb = *(const f32x4*)(bl2 + c0);
    const f32x4 gg = *(const f32x4*)(g + c0);
    const f32x4 ee = *(const f32x4*)(be + c0);
    #pragma unroll 1
    for (int r = 0; r < 8; ++r) {
        const long row = (long)blockIdx.x * 32 + wave * 8 + r;
        const f32x4 p0 = *(const f32x4*)(PART + row * DM + c0);
        const f32x4 p1 = *(const f32x4*)(PART + (long)MROWS * DM + row * DM + c0);
        const bf16x4 rr = *(const bf16x4*)(residb + row * DM + c0);
        float v[4]; float s = 0.f, s2 = 0.f;
        #pragma unroll
        for (int j = 0; j < 4; ++j) {
            v[j] = p0[j] + p1[j] + bb[j] + bf2f(rr[j]);
            s += v[j]; s2 += v[j] * v[j];
        }
        #pragma unroll
        for (int o = 1; o < 64; o <<= 1) {
            s  += __shfl_xor(s,  o, 64);
            s2 += __shfl_xor(s2, o, 64);
        }
        const float mean = s * (1.f / DM);
        const float var  = s2 * (1.f / DM) - mean * mean;
        const float rstd = rsqrtf(var + 1e-5f);
        float o4[4];
        #pragma unroll
        for (int j = 0; j < 4; ++j)
            o4[j] = (v[j] - mean) * rstd * gg[j] + ee[j];
        if (outb) {
            bf16x4 ob;
            #pragma unroll
            for (int j = 0; j < 4; ++j) ob[j] = f2bf(o4[j]);
            *(bf16x4*)(outb + row * DM + c0) = ob;
        }
        if (outq) {
            const f32x4 pp = *(const f32x4*)(pos + row * DM + c0);
            bf16x4 oq;
            #pragma unroll
            for (int j = 0; j < 4; ++j) oq[j] = f2bf(o4[j] + pp[j]);
            *(bf16x4*)(outq + row * DM + c0) = oq;
        }
        if (outf) {
            f32x4 of;
            #pragma unroll
            for (int j = 0; j < 4; ++j) of[j] = o4[j];
            *(f32x4*)(outf + row * DM + c0) = of;
        }
    }
}

// ---------------------------------------------------------------------------
// Deformable attention sampling v3 (unchanged, grid 2720).
// ---------------------------------------------------------------------------
__global__ __launch_bounds__(256) void deform_attn_v3(
    const short* __restrict__ Vb,    // (NB*NH, LEN, 32) bf16
    const float* __restrict__ OFF,   // (MROWS, 256)
    const float* __restrict__ AW,    // (MROWS, 128)
    const float* __restrict__ vr,    // (NB, NLV, 2)
    bf16x4* __restrict__ ATTb)       // (MROWS, 64) bf16x4
{
    const int starts[5] = {0, 4096, 5120, 5376, 5440};
    const int dims[4]   = {64, 32, 16, 8};

    const int wave = threadIdx.x >> 6;
    const int lane = threadIdx.x & 63;
    const int h    = lane >> 3;
    const int d4   = lane & 7;

    const int gq = blockIdx.x * 4 + wave;
    const int n  = gq / LEN;
    const int q  = gq % LEN;

    int lq = 3;
    if (q < 4096) lq = 0; else if (q < 5120) lq = 1; else if (q < 5376) lq = 2;
    const int r  = q - starts[lq];
    const int Wq = dims[lq];
    const int gy = r / Wq, gx = r % Wq;
    const float vrxq = vr[(n * NLV + lq) * 2 + 0];
    const float vryq = vr[(n * NLV + lq) * 2 + 1];
    const float rx = (gx + 0.5f) / (vrxq * Wq);
    const float ry = (gy + 0.5f) / (vryq * Wq);

    const long row = (long)n * LEN + q;

    const float* awp = AW + row * 128 + h * 16;
    float a[16];
    float mx = -1e30f;
    #pragma unroll
    for (int i = 0; i < 16; ++i) { a[i] = awp[i]; mx = fmaxf(mx, a[i]); }
    float s = 0.f;
    #pragma unroll
    for (int i = 0; i < 16; ++i) { a[i] = __expf(a[i] - mx); s += a[i]; }
    const float inv = 1.f / s;

    const float* offp = OFF + row * 256 + h * 32;

    float4 acc = {0.f, 0.f, 0.f, 0.f};
    #pragma unroll
    for (int lvl = 0; lvl < NLV; ++lvl) {
        const int Hl = dims[lvl];
        const int Wl = Hl;
        const float fW = (float)Wl;
        const int sb = starts[lvl];
        const float lx = rx * vr[(n * NLV + lvl) * 2 + 0];
        const float ly = ry * vr[(n * NLV + lvl) * 2 + 1];
        const short* vb = Vb + ((long)(n * NH + h) * LEN + sb) * 32 + d4 * 4;
        #pragma unroll
        for (int p = 0; p < NPT; ++p) {
            const float ox = offp[lvl * 8 + p * 2 + 0];
            const float oy = offp[lvl * 8 + p * 2 + 1];
            const float x = fmaf(lx, fW, ox) - 0.5f;
            const float y = fmaf(ly, fW, oy) - 0.5f;
            const float x0f = floorf(x), y0f = floorf(y);
            const int ix0 = (int)x0f, iy0 = (int)y0f;
            const float wx1 = x - x0f, wy1 = y - y0f;
            const float wx0 = 1.f - wx1, wy0 = 1.f - wy1;

            const bool vx0 = (ix0 >= 0)     && (ix0 < Wl);
            const bool vx1 = (ix0 + 1 >= 0) && (ix0 + 1 < Wl);
            const bool vy0 = (iy0 >= 0)     && (iy0 < Hl);
            const bool vy1 = (iy0 + 1 >= 0) && (iy0 + 1 < Hl);
            const int cx0 = min(max(ix0, 0), Wl - 1);
            const int cx1 = min(max(ix0 + 1, 0), Wl - 1);
            const int cy0 = min(max(iy0, 0), Hl - 1);
            const int cy1 = min(max(iy0 + 1, 0), Hl - 1);

            const float w00 = (vx0 && vy0) ? wx0 * wy0 : 0.f;
            const float w10 = (vx1 && vy0) ? wx1 * wy0 : 0.f;
            const float w01 = (vx0 && vy1) ? wx0 * wy1 : 0.f;
            const float w11 = (vx1 && vy1) ? wx1 * wy1 : 0.f;

            const bf16x4 g00 = *(const bf16x4*)(vb + (long)(cy0 * Wl + cx0) * 32);
            const bf16x4 g10 = *(const bf16x4*)(vb + (long)(cy0 * Wl + cx1) * 32);
            const bf16x4 g01 = *(const bf16x4*)(vb + (long)(cy1 * Wl + cx0) * 32);
            const bf16x4 g11 = *(const bf16x4*)(vb + (long)(cy1 * Wl + cx1) * 32);

            const float awv = a[lvl * 4 + p] * inv;
            #pragma unroll
            for (int e = 0; e < 4; ++e) {
                float sv = w00 * bf2f(g00[e]) + w10 * bf2f(g10[e])
                         + w01 * bf2f(g01[e]) + w11 * bf2f(g11[e]);
                (&acc.x)[e] += awv * sv;
            }
        }
    }
    bf16x4 ob;
    ob[0] = f2bf(acc.x); ob[1] = f2bf(acc.y);
    ob[2] = f2bf(acc.z); ob[3] = f2bf(acc.w);
    ATTb[row * 64 + h * 8 + d4] = ob;
}

// ---------------------------------------------------------------------------
extern "C" void kernel_launch(void* const* d_in, const int* in_sizes, int n_in,
                              void* d_out, int out_size, void* d_ws, size_t ws_size,
                              hipStream_t stream)
{
    const float* src = (const float*)d_in[0];
    const float* pos = (const float*)d_in[1];
    const float* vr  = (const float*)d_in[2];
    const float* Wv_   = (const float*)d_in[3];
    const float* bv_   = (const float*)d_in[4];
    const float* Woff_ = (const float*)d_in[5];
    const float* boff_ = (const float*)d_in[6];
    const float* Wa_   = (const float*)d_in[7];
    const float* ba_   = (const float*)d_in[8];
    const float* Wo_   = (const float*)d_in[9];
    const float* bo_   = (const float*)d_in[10];
    const float* g1_   = (const float*)d_in[11];
    const float* be1_  = (const float*)d_in[12];
    const float* Wl1_  = (const float*)d_in[13];
    const float* bl1_  = (const float*)d_in[14];
    const float* Wl2_  = (const float*)d_in[15];
    const float* bl2_  = (const float*)d_in[16];
    const float* g2_   = (const float*)d_in[17];
    const float* be2_  = (const float*)d_in[18];

    const long SZ = (long)MROWS * DM;        // 2,785,280 elements
    float* ws = (float*)d_ws;
    float* OFF  = ws;                         // f32 M x 256
    float* AW   = OFF + SZ;                   // f32 M x 128
    short* Vb   = (short*)(AW + (long)MROWS * 128);  // bf16 (NB*NH, LEN, 32)
    short* curb = Vb   + SZ;                  // bf16 M x 256 (trunk)
    short* qb   = curb + SZ;                  // bf16 M x 256 (trunk + pos)
    short* ATTb = qb   + SZ;                  // bf16 M x 256
    short* XAb  = ATTb + SZ;                  // bf16 M x 256 (LN1 out)
    short* FFNb = XAb  + SZ;                  // bf16 M x 1024
    short* Wt   = FFNb + (long)MROWS * DFFN;  // 2 x 753664 bf16 weights
    float* PART = (float*)(Wt + 2L * 753664); // f32 2 x M x 256 partials

    const dim3 blk(256);
    const int GLN = MROWS / 32;               // 340

    hipLaunchKernelGGL(prep_all, dim3(1472 + SZ / 4 / 256), blk, 0, stream,
                       Wv_, Woff_, Wa_, Wo_, Wl1_, Wl2_, Wt,
                       (const float4*)src, (const float4*)pos,
                       (bf16x4*)curb, (bf16x4*)qb);

    for (int l = 0; l < 2; ++l) {
        const short* Wbase = Wt + (long)l * 753664;
        const float* bv   = bv_   + (long)l * DM;
        const float* boff = boff_ + (long)l * 256;
        const float* ba   = ba_   + (long)l * 128;
        const float* bo   = bo_   + (long)l * DM;
        const float* g1   = g1_   + (long)l * DM;
        const float* be1  = be1_  + (long)l * DM;
        const float* bl1  = bl1_  + (long)l * DFFN;
        const float* bl2  = bl2_  + (long)l * DM;
        const float* g2   = g2_   + (long)l * DM;
        const float* be2  = be2_  + (long)l * DM;

        // [Vb | OFF | AW] = [curb | qb] @ [Wv|Woff|Wa]   (5 panels x 43)
        hipLaunchKernelGGL(qkv_panel, dim3(5, 43), blk, 0, stream,
                           curb, qb, Wbase, bv, boff, ba, Vb, OFF, AW);
        hipLaunchKernelGGL(deform_attn_v3, dim3(MROWS / 4), blk, 0, stream,
                           Vb, OFF, AW, vr, (bf16x4*)ATTb);
        // XAb = bf16( LN(curb + ATT@Wo + bo) )
        hipLaunchKernelGGL((gemm_ln<256>), dim3(GLN), blk, 0, stream,
                           ATTb, Wbase + 163840, bo, curb, g1, be1,
                           XAb, (short*)nullptr, (float*)nullptr,
                           (const float*)nullptr);
        // FFNb = relu(XAb @ Wl1 + bl1)   (8 panels x 43)
        hipLaunchKernelGGL(ffn1_panel, dim3(8, 43), blk, 0, stream,
                           XAb, Wbase + 229376, bl1, FFNb);
        // ln2 split-K partials (4 panels x 64), then finisher
        hipLaunchKernelGGL(ln2_panel, dim3(4, 64), blk, 0, stream,
                           FFNb, Wbase + 491520, PART);
        if (l == 0) {
            hipLaunchKernelGGL(ln2_fin_k, dim3(GLN), blk, 0, stream,
                               PART, XAb, bl2, g2, be2,
                               curb, qb, (float*)nullptr, pos);
        } else {
            hipLaunchKernelGGL(ln2_fin_k, dim3(GLN), blk, 0, stream,
                               PART, XAb, bl2, g2, be2,
                               (short*)nullptr, (short*)nullptr,
                               (float*)d_out, (const float*)nullptr);
        }
    }
}

// Round 8
// 297.026 us; speedup vs baseline: 1.2294x; 1.2294x over previous
//
#include <hip/hip_runtime.h>
#include <math.h>

#define LEN   5440
#define NB    2
#define MROWS (NB * LEN)   // 10880
#define DM    256
#define NH    8
#define HD    32
#define NLV   4
#define NPT   4
#define DFFN  1024

typedef __attribute__((ext_vector_type(8))) short bf16x8;
typedef __attribute__((ext_vector_type(4))) short bf16x4;
typedef __attribute__((ext_vector_type(4))) float f32x4;

#define MFMA16 __builtin_amdgcn_mfma_f32_16x16x32_bf16

__device__ __forceinline__ short f2bf(float f) {
    union { float f; unsigned u; } cv; cv.f = f;
    unsigned r = cv.u + 0x7fffu + ((cv.u >> 16) & 1u);   // RNE
    return (short)(r >> 16);
}
__device__ __forceinline__ float bf2f(short s) {
    union { unsigned u; float f; } cv;
    cv.u = ((unsigned)(unsigned short)s) << 16;
    return cv.f;
}

__device__ __forceinline__ void gload16(const short* g, short* l) {
    __builtin_amdgcn_global_load_lds(
        (__attribute__((address_space(1))) void*)g,
        (__attribute__((address_space(3))) void*)l, 16, 0, 0);
}

template <int N> __device__ __forceinline__ void vmwait();
template <> __device__ __forceinline__ void vmwait<0>() { asm volatile("s_waitcnt vmcnt(0)" ::: "memory"); }
template <> __device__ __forceinline__ void vmwait<8>() { asm volatile("s_waitcnt vmcnt(8)" ::: "memory"); }
template <> __device__ __forceinline__ void vmwait<9>() { asm volatile("s_waitcnt vmcnt(9)" ::: "memory"); }

// BK=64 rows are 128B = 8 x 16B chunks; phys_chunk = logical_chunk ^ (row&7).
// Involution applied on BOTH the staging source and the ds_read address.

// ---------------------------------------------------------------------------
// Merged one-shot prep (unchanged).
// ---------------------------------------------------------------------------
__global__ __launch_bounds__(256) void prep_all(
    const float* __restrict__ Wv,  const float* __restrict__ Woff,
    const float* __restrict__ Wa,  const float* __restrict__ Wo,
    const float* __restrict__ Wl1, const float* __restrict__ Wl2,
    short* __restrict__ out,
    const float4* __restrict__ s4, const float4* __restrict__ p4,
    bf16x4* __restrict__ curb, bf16x4* __restrict__ qb)
{
    __shared__ short T[32][33];
    if (blockIdx.x >= 1472) {
        const int i = (blockIdx.x - 1472) * 256 + threadIdx.x;
        float4 s = s4[i], p = p4[i];
        bf16x4 c, q;
        c[0] = f2bf(s.x); c[1] = f2bf(s.y); c[2] = f2bf(s.z); c[3] = f2bf(s.w);
        q[0] = f2bf(s.x + p.x); q[1] = f2bf(s.y + p.y);
        q[2] = f2bf(s.z + p.z); q[3] = f2bf(s.w + p.w);
        curb[i] = c; qb[i] = q;
        return;
    }
    int bx = blockIdx.x;
    int l  = bx / 736;
    int t  = bx % 736;
    const float* src; int K, N; long doff;
    if      (t < 64)  { src = Wv;   K = 256;  N = 256;  doff = 0;      }
    else if (t < 128) { src = Woff; K = 256;  N = 256;  doff = 65536;  t -= 64;  }
    else if (t < 160) { src = Wa;   K = 256;  N = 128;  doff = 131072; t -= 128; }
    else if (t < 224) { src = Wo;   K = 256;  N = 256;  doff = 163840; t -= 160; }
    else if (t < 480) { src = Wl1;  K = 256;  N = 1024; doff = 229376; t -= 224; }
    else              { src = Wl2;  K = 1024; N = 256;  doff = 491520; t -= 480; }
    src += (long)l * K * N;
    short* dst = out + (long)l * 753664 + doff;

    const int ntx = N / 32;
    const int n0 = (t % ntx) * 32, k0 = (t / ntx) * 32;

    const int tid = threadIdx.x;
    {
        const int n = tid & 31, kq = tid >> 5;
        #pragma unroll
        for (int i = 0; i < 4; ++i) {
            int k = kq * 4 + i;
            T[n][k] = f2bf(src[(long)(k0 + k) * N + n0 + n]);
        }
    }
    __syncthreads();
    {
        const int k = tid & 31, nq = tid >> 5;
        #pragma unroll
        for (int i = 0; i < 4; ++i) {
            int n = nq * 4 + i;
            dst[(long)(n0 + n) * K + k0 + k] = T[n][k];
        }
    }
}

// ---------------------------------------------------------------------------
// MFMA bf16 GEMM core v3 (R6-verified): 128x128 tile, BK=64, global_load_lds
// 2-buffer counted-vmcnt staging, 8-chunk XOR swizzle. astr/wstr allow
// K-slice views into wider rows (ln2 split-K).
// OMODE: 0 f32 row-major (+optional bias), 1 bf16 row-major, 2 bf16 V planes.
// ---------------------------------------------------------------------------
template <int RELU, int OMODE, int K>
__device__ __forceinline__ void gemm_core128_v3(
    short* As, short* Bs,
    const short* __restrict__ A, int astr,
    const short* __restrict__ Wt, int wstr,
    const float* __restrict__ bias, float* __restrict__ Cf,
    short* __restrict__ Cb, int ldc, int m0, int wrow0, int ccol0)
{
    constexpr int NT = K / 64;
    static_assert(NT >= 4 && (NT & 1) == 0, "NT even >= 4");
    const int t    = threadIdx.x;
    const int wave = t >> 6, lane = t & 63;
    const int wm   = (wave & 1) * 64;
    const int wn   = (wave >> 1) * 64;
    const int lm   = lane & 15;
    const int chkg = lane >> 4;

    // staging: per matrix, wave w covers rows [w*32, w*32+32), 4 issues of
    // 8 rows x 8 chunks; source chunk pre-swizzled, LDS dest linear.
    const short* aS[4]; const short* bS[4];
    int ldst[4];
    #pragma unroll
    for (int j = 0; j < 4; ++j) {
        const int row = wave * 32 + j * 8 + (lane >> 3);
        const int sc  = (lane & 7) ^ (row & 7);
        aS[j] = A  + (long)(m0 + row) * astr + sc * 8;
        bS[j] = Wt + (long)(wrow0 + row) * wstr + sc * 8;
        ldst[j] = wave * 2048 + j * 512;       // shorts, wave-uniform
    }

    // fragment read offsets (shorts), kk=0; kk=1 = offset ^ 32
    int offA[4], offB[4];
    #pragma unroll
    for (int s = 0; s < 4; ++s) {
        const int r = wm + s * 16 + lm;
        offA[s] = r * 64 + ((chkg ^ (r & 7)) * 8);
    }
    #pragma unroll
    for (int u = 0; u < 4; ++u) {
        const int r = wn + u * 16 + lm;
        offB[u] = r * 64 + ((chkg ^ (r & 7)) * 8);
    }

    f32x4 acc[4][4] = {};

#define STG3(BUF, KT) do {                                            \
        const int _ko = (KT) * 64;                                    \
        _Pragma("unroll")                                             \
        for (int j = 0; j < 4; ++j)                                   \
            gload16(aS[j] + _ko, As + (BUF) * 8192 + ldst[j]);        \
        _Pragma("unroll")                                             \
        for (int j = 0; j < 4; ++j)                                   \
            gload16(bS[j] + _ko, Bs + (BUF) * 8192 + ldst[j]);        \
    } while (0)

#define GB3(T, BUF, WN, DOSTAGE) do {                                 \
        vmwait<WN>();                                                 \
        __builtin_amdgcn_s_barrier();                                 \
        bf16x8 a0[4], a1[4], b0[4], b1[4];                            \
        _Pragma("unroll")                                             \
        for (int s = 0; s < 4; ++s) {                                 \
            a0[s] = *(const bf16x8*)(As + (BUF) * 8192 + offA[s]);    \
            a1[s] = *(const bf16x8*)(As + (BUF) * 8192 + (offA[s] ^ 32)); \
        }                                                             \
        _Pragma("unroll")                                             \
        for (int u = 0; u < 4; ++u) {                                 \
            b0[u] = *(const bf16x8*)(Bs + (BUF) * 8192 + offB[u]);    \
            b1[u] = *(const bf16x8*)(Bs + (BUF) * 8192 + (offB[u] ^ 32)); \
        }                                                             \
        asm volatile("s_waitcnt lgkmcnt(0)" ::: "memory");            \
        __builtin_amdgcn_s_barrier();                                 \
        __builtin_amdgcn_sched_barrier(0);                            \
        if (DOSTAGE) STG3(BUF, (T) + 2);                              \
        _Pragma("unroll")                                             \
        for (int s = 0; s < 4; ++s)                                   \
            _Pragma("unroll")                                         \
            for (int u = 0; u < 4; ++u) {                             \
                acc[s][u] = MFMA16(a0[s], b0[u], acc[s][u], 0, 0, 0); \
                acc[s][u] = MFMA16(a1[s], b1[u], acc[s][u], 0, 0, 0); \
            }                                                         \
    } while (0)

    STG3(0, 0);
    STG3(1, 1);
    for (int tt = 0; tt < NT - 2; tt += 2) {
        GB3(tt,     0, 8, true);
        GB3(tt + 1, 1, 8, true);
    }
    GB3(NT - 2, 0, 8, false);
    GB3(NT - 1, 1, 0, false);
#undef GB3
#undef STG3

    const int col = lane & 15;
    const int rq  = (lane >> 4) * 4;
    #pragma unroll
    for (int s = 0; s < 4; ++s) {
        #pragma unroll
        for (int u = 0; u < 4; ++u) {
            const int gn = ccol0 + wn + u * 16 + col;
            const float bb = bias ? bias[gn] : 0.f;
            #pragma unroll
            for (int r = 0; r < 4; ++r) {
                const int gm = m0 + wm + s * 16 + rq + r;
                float v = acc[s][u][r] + bb;
                if (RELU) v = fmaxf(v, 0.f);
                if (OMODE == 0) {
                    Cf[(long)gm * ldc + gn] = v;
                } else if (OMODE == 1) {
                    Cb[(long)gm * ldc + gn] = f2bf(v);
                } else {
                    const int n   = gm / LEN;
                    const int pix = gm - n * LEN;
                    const int h   = gn >> 5, d = gn & 31;
                    Cb[((long)(n * NH + h) * LEN + pix) * 32 + d] = f2bf(v);
                }
            }
        }
    }
}

template <int RELU, int OMODE, int K>
__global__ __launch_bounds__(256) void gemm128v3(
    const short* __restrict__ A, const short* __restrict__ Wt,
    const float* __restrict__ bias, float* Cf, short* Cb, int ldc)
{
    __shared__ __align__(16) short As[2 * 128 * 64];
    __shared__ __align__(16) short Bs[2 * 128 * 64];
    gemm_core128_v3<RELU, OMODE, K>(As, Bs, A, K, Wt, K, bias, Cf, Cb, ldc,
                                    blockIdx.y * 128, blockIdx.x * 128,
                                    blockIdx.x * 128);
}

// Fused query-side GEMM: [Vb | OFF | AW] over N=640.
__global__ __launch_bounds__(256) void gemm_qkv128(
    const short* __restrict__ curb, const short* __restrict__ qb,
    const short* __restrict__ Wt, const float* __restrict__ bv,
    const float* __restrict__ boff, const float* __restrict__ ba,
    short* __restrict__ Vb, float* __restrict__ OFF, float* __restrict__ AW)
{
    __shared__ __align__(16) short As[2 * 128 * 64];
    __shared__ __align__(16) short Bs[2 * 128 * 64];
    const int n0 = blockIdx.x * 128;   // 0,128,256,384,512
    if (n0 < 256) {
        gemm_core128_v3<0, 2, 256>(As, Bs, curb, 256, Wt, 256, bv,
                                   (float*)nullptr, Vb, 256,
                                   blockIdx.y * 128, n0, n0);
    } else if (n0 < 512) {
        gemm_core128_v3<0, 0, 256>(As, Bs, qb, 256, Wt, 256, boff, OFF,
                                   (short*)nullptr, 256,
                                   blockIdx.y * 128, n0, n0 - 256);
    } else {
        gemm_core128_v3<0, 0, 256>(As, Bs, qb, 256, Wt, 256, ba, AW,
                                   (short*)nullptr, 128,
                                   blockIdx.y * 128, n0, n0 - 512);
    }
}

// ln2 split-K partials through the SAME verified M128 pipeline:
// grid (4, 85): kk = x>>1 (K-half), nc = x&1 (N-panel). B-traffic
// 174 MB -> 44 MB vs the M32 version. A rows are K=512 slices of
// 1024-stride FFNb rows; W rows are 512-slices of 1024-stride Wl2t rows.
__global__ __launch_bounds__(256) void ln2_part128(
    const short* __restrict__ FFNb, const short* __restrict__ W0,
    float* __restrict__ PART)
{
    __shared__ __align__(16) short As[2 * 128 * 64];
    __shared__ __align__(16) short Bs[2 * 128 * 64];
    const int kk = blockIdx.x >> 1, nc = blockIdx.x & 1;
    gemm_core128_v3<0, 0, 512>(As, Bs,
                               FFNb + kk * 512, 1024,
                               W0 + (long)nc * 128 * 1024 + kk * 512, 1024,
                               (const float*)nullptr,
                               PART + (long)kk * MROWS * DM,
                               (short*)nullptr, 256,
                               blockIdx.y * 128, 0, nc * 128);
}

// ---------------------------------------------------------------------------
// Fused GEMM + residual(bf16) + LayerNorm, M32 tile, N=256, BK=64 (R6).
// ---------------------------------------------------------------------------
template <int K>
__global__ __launch_bounds__(256) void gemm_ln(
    const short* __restrict__ A, const short* __restrict__ Wt,
    const float* __restrict__ bias, const short* __restrict__ residb,
    const float* __restrict__ g, const float* __restrict__ be,
    short* __restrict__ outb, short* __restrict__ outq,
    float* __restrict__ outf, const float* __restrict__ pos)
{
    constexpr int NT = K / 64;
    static_assert(NT >= 4 && (NT & 1) == 0, "NT even >= 4");
    __shared__ __align__(16) short As[2 * 32 * 64];    // 2 x 2048
    __shared__ __align__(16) short Bs[2 * 256 * 64];   // 2 x 16384
    __shared__ float red[2][32][2];

    const int t    = threadIdx.x;
    const int wave = t >> 6, lane = t & 63;
    const int wm   = (wave & 1) * 16;
    const int wn   = (wave >> 1) * 128;
    const int lm   = lane & 15;
    const int chkg = lane >> 4;
    const int rq   = chkg * 4;
    const int m0   = blockIdx.x * 32;

    // resid prefetch FIRST (oldest vmcnt events)
    short rr[8][4];
    #pragma unroll
    for (int u = 0; u < 8; ++u)
        #pragma unroll
        for (int r = 0; r < 4; ++r)
            rr[u][r] = residb[(long)(m0 + wm + rq + r) * DM + wn + u * 16 + lm];
    asm volatile("" ::: "memory");

    // staging: A = 1 issue (block-wide 32 rows x 8 chunks), B = 8 issues
    const int arow = t >> 3;
    const short* aSp = A + (long)(m0 + arow) * K + (((t & 7) ^ (arow & 7)) * 8);
    const int aDst = wave * 512;
    const short* bSp[8]; int bDst[8];
    #pragma unroll
    for (int j = 0; j < 8; ++j) {
        const int row = wave * 64 + j * 8 + (lane >> 3);
        const int sc  = (lane & 7) ^ (row & 7);
        bSp[j] = Wt + (long)row * K + sc * 8;
        bDst[j] = wave * 4096 + j * 512;
    }

    const int offA = (wm + lm) * 64 + ((chkg ^ ((wm + lm) & 7)) * 8);
    int offB[8];
    #pragma unroll
    for (int u = 0; u < 8; ++u) {
        const int r = wn + u * 16 + lm;
        offB[u] = r * 64 + ((chkg ^ (r & 7)) * 8);
    }

    f32x4 acc[8] = {};

#define STGL(BUF, KT) do {                                            \
        const int _ko = (KT) * 64;                                    \
        gload16(aSp + _ko, As + (BUF) * 2048 + aDst);                 \
        _Pragma("unroll")                                             \
        for (int j = 0; j < 8; ++j)                                   \
            gload16(bSp[j] + _ko, Bs + (BUF) * 16384 + bDst[j]);      \
    } while (0)

#define GBLN(T, BUF, WN, DOSTAGE) do {                                \
        vmwait<WN>();                                                 \
        __builtin_amdgcn_s_barrier();                                 \
        bf16x8 af0 = *(const bf16x8*)(As + (BUF) * 2048 + offA);      \
        bf16x8 af1 = *(const bf16x8*)(As + (BUF) * 2048 + (offA ^ 32)); \
        bf16x8 b0[8], b1[8];                                          \
        _Pragma("unroll")                                             \
        for (int u = 0; u < 8; ++u) {                                 \
            b0[u] = *(const bf16x8*)(Bs + (BUF) * 16384 + offB[u]);   \
            b1[u] = *(const bf16x8*)(Bs + (BUF) * 16384 + (offB[u] ^ 32)); \
        }                                                             \
        asm volatile("s_waitcnt lgkmcnt(0)" ::: "memory");            \
        __builtin_amdgcn_s_barrier();                                 \
        __builtin_amdgcn_sched_barrier(0);                            \
        if (DOSTAGE) STGL(BUF, (T) + 2);                              \
        _Pragma("unroll")                                             \
        for (int u = 0; u < 8; ++u) {                                 \
            acc[u] = MFMA16(af0, b0[u], acc[u], 0, 0, 0);             \
            acc[u] = MFMA16(af1, b1[u], acc[u], 0, 0, 0);             \
        }                                                             \
    } while (0)

    STGL(0, 0);
    STGL(1, 1);
    for (int tt = 0; tt < NT - 2; tt += 2) {
        GBLN(tt,     0, 9, true);
        GBLN(tt + 1, 1, 9, true);
    }
    GBLN(NT - 2, 0, 9, false);
    GBLN(NT - 1, 1, 0, false);
#undef GBLN
#undef STGL

    #pragma unroll
    for (int u = 0; u < 8; ++u) {
        const int gn = wn + u * 16 + lm;
        const float bb = bias[gn];
        #pragma unroll
        for (int r = 0; r < 4; ++r)
            acc[u][r] += bb + bf2f(rr[u][r]);
    }

    float rs[4], r2[4];
    #pragma unroll
    for (int r = 0; r < 4; ++r) {
        float s = 0.f, s2 = 0.f;
        #pragma unroll
        for (int u = 0; u < 8; ++u) { const float v = acc[u][r]; s += v; s2 += v * v; }
        rs[r] = s; r2[r] = s2;
    }
    #pragma unroll
    for (int o = 1; o < 16; o <<= 1)
        #pragma unroll
        for (int r = 0; r < 4; ++r) {
            rs[r] += __shfl_xor(rs[r], o, 64);
            r2[r] += __shfl_xor(r2[r], o, 64);
        }
    if (lm == 0) {
        #pragma unroll
        for (int r = 0; r < 4; ++r) {
            red[wave >> 1][wm + rq + r][0] = rs[r];
            red[wave >> 1][wm + rq + r][1] = r2[r];
        }
    }
    __syncthreads();
    #pragma unroll
    for (int r = 0; r < 4; ++r) {
        const int row = wm + rq + r;
        const float ts = red[0][row][0] + red[1][row][0];
        const float t2 = red[0][row][1] + red[1][row][1];
        const float mean = ts * (1.f / DM);
        const float var  = t2 * (1.f / DM) - mean * mean;
        rs[r] = mean;
        r2[r] = rsqrtf(var + 1e-5f);
    }
    #pragma unroll
    for (int u = 0; u < 8; ++u) {
        const int gn = wn + u * 16 + lm;
        const float gg = g[gn], bbe = be[gn];
        #pragma unroll
        for (int r = 0; r < 4; ++r) {
            const long gm = m0 + wm + rq + r;
            const float o = (acc[u][r] - rs[r]) * r2[r] * gg + bbe;
            if (outb) outb[gm * DM + gn] = f2bf(o);
            if (outq) outq[gm * DM + gn] = f2bf(o + pos[gm * DM + gn]);
            if (outf) outf[gm * DM + gn] = o;
        }
    }
}

// ---------------------------------------------------------------------------
// Split-K ln2 finisher (unchanged).
// ---------------------------------------------------------------------------
__global__ __launch_bounds__(256) void ln2_fin_k(
    const float* __restrict__ PART, const short* __restrict__ residb,
    const float* __restrict__ bl2, const float* __restrict__ g,
    const float* __restrict__ be, short* __restrict__ outb,
    short* __restrict__ outq, float* __restrict__ outf,
    const float* __restrict__ pos)
{
    const int wave = threadIdx.x >> 6, lane = threadIdx.x & 63;
    const int c0 = lane * 4;
    const f32x4 bb = *(const f32x4*)(bl2 + c0);
    const f32x4 gg = *(const f32x4*)(g + c0);
    const f32x4 ee = *(const f32x4*)(be + c0);
    #pragma unroll 1
    for (int r = 0; r < 8; ++r) {
        const long row = (long)blockIdx.x * 32 + wave * 8 + r;
        const f32x4 p0 = *(const f32x4*)(PART + row * DM + c0);
        const f32x4 p1 = *(const f32x4*)(PART + (long)MROWS * DM + row * DM + c0);
        const bf16x4 rr = *(const bf16x4*)(residb + row * DM + c0);
        float v[4]; float s = 0.f, s2 = 0.f;
        #pragma unroll
        for (int j = 0; j < 4; ++j) {
            v[j] = p0[j] + p1[j] + bb[j] + bf2f(rr[j]);
            s += v[j]; s2 += v[j] * v[j];
        }
        #pragma unroll
        for (int o = 1; o < 64; o <<= 1) {
            s  += __shfl_xor(s,  o, 64);
            s2 += __shfl_xor(s2, o, 64);
        }
        const float mean = s * (1.f / DM);
        const float var  = s2 * (1.f / DM) - mean * mean;
        const float rstd = rsqrtf(var + 1e-5f);
        float o4[4];
        #pragma unroll
        for (int j = 0; j < 4; ++j)
            o4[j] = (v[j] - mean) * rstd * gg[j] + ee[j];
        if (outb) {
            bf16x4 ob;
            #pragma unroll
            for (int j = 0; j < 4; ++j) ob[j] = f2bf(o4[j]);
            *(bf16x4*)(outb + row * DM + c0) = ob;
        }
        if (outq) {
            const f32x4 pp = *(const f32x4*)(pos + row * DM + c0);
            bf16x4 oq;
            #pragma unroll
            for (int j = 0; j < 4; ++j) oq[j] = f2bf(o4[j] + pp[j]);
            *(bf16x4*)(outq + row * DM + c0) = oq;
        }
        if (outf) {
            f32x4 of;
            #pragma unroll
            for (int j = 0; j < 4; ++j) of[j] = o4[j];
            *(f32x4*)(outf + row * DM + c0) = of;
        }
    }
}

// ---------------------------------------------------------------------------
// Deformable attention sampling v3 (unchanged, grid 2720).
// ---------------------------------------------------------------------------
__global__ __launch_bounds__(256) void deform_attn_v3(
    const short* __restrict__ Vb,    // (NB*NH, LEN, 32) bf16
    const float* __restrict__ OFF,   // (MROWS, 256)
    const float* __restrict__ AW,    // (MROWS, 128)
    const float* __restrict__ vr,    // (NB, NLV, 2)
    bf16x4* __restrict__ ATTb)       // (MROWS, 64) bf16x4
{
    const int starts[5] = {0, 4096, 5120, 5376, 5440};
    const int dims[4]   = {64, 32, 16, 8};

    const int wave = threadIdx.x >> 6;
    const int lane = threadIdx.x & 63;
    const int h    = lane >> 3;
    const int d4   = lane & 7;

    const int gq = blockIdx.x * 4 + wave;
    const int n  = gq / LEN;
    const int q  = gq % LEN;

    int lq = 3;
    if (q < 4096) lq = 0; else if (q < 5120) lq = 1; else if (q < 5376) lq = 2;
    const int r  = q - starts[lq];
    const int Wq = dims[lq];
    const int gy = r / Wq, gx = r % Wq;
    const float vrxq = vr[(n * NLV + lq) * 2 + 0];
    const float vryq = vr[(n * NLV + lq) * 2 + 1];
    const float rx = (gx + 0.5f) / (vrxq * Wq);
    const float ry = (gy + 0.5f) / (vryq * Wq);

    const long row = (long)n * LEN + q;

    const float* awp = AW + row * 128 + h * 16;
    float a[16];
    float mx = -1e30f;
    #pragma unroll
    for (int i = 0; i < 16; ++i) { a[i] = awp[i]; mx = fmaxf(mx, a[i]); }
    float s = 0.f;
    #pragma unroll
    for (int i = 0; i < 16; ++i) { a[i] = __expf(a[i] - mx); s += a[i]; }
    const float inv = 1.f / s;

    const float* offp = OFF + row * 256 + h * 32;

    float4 acc = {0.f, 0.f, 0.f, 0.f};
    #pragma unroll
    for (int lvl = 0; lvl < NLV; ++lvl) {
        const int Hl = dims[lvl];
        const int Wl = Hl;
        const float fW = (float)Wl;
        const int sb = starts[lvl];
        const float lx = rx * vr[(n * NLV + lvl) * 2 + 0];
        const float ly = ry * vr[(n * NLV + lvl) * 2 + 1];
        const short* vb = Vb + ((long)(n * NH + h) * LEN + sb) * 32 + d4 * 4;
        #pragma unroll
        for (int p = 0; p < NPT; ++p) {
            const float ox = offp[lvl * 8 + p * 2 + 0];
            const float oy = offp[lvl * 8 + p * 2 + 1];
            const float x = fmaf(lx, fW, ox) - 0.5f;
            const float y = fmaf(ly, fW, oy) - 0.5f;
            const float x0f = floorf(x), y0f = floorf(y);
            const int ix0 = (int)x0f, iy0 = (int)y0f;
            const float wx1 = x - x0f, wy1 = y - y0f;
            const float wx0 = 1.f - wx1, wy0 = 1.f - wy1;

            const bool vx0 = (ix0 >= 0)     && (ix0 < Wl);
            const bool vx1 = (ix0 + 1 >= 0) && (ix0 + 1 < Wl);
            const bool vy0 = (iy0 >= 0)     && (iy0 < Hl);
            const bool vy1 = (iy0 + 1 >= 0) && (iy0 + 1 < Hl);
            const int cx0 = min(max(ix0, 0), Wl - 1);
            const int cx1 = min(max(ix0 + 1, 0), Wl - 1);
            const int cy0 = min(max(iy0, 0), Hl - 1);
            const int cy1 = min(max(iy0 + 1, 0), Hl - 1);

            const float w00 = (vx0 && vy0) ? wx0 * wy0 : 0.f;
            const float w10 = (vx1 && vy0) ? wx1 * wy0 : 0.f;
            const float w01 = (vx0 && vy1) ? wx0 * wy1 : 0.f;
            const float w11 = (vx1 && vy1) ? wx1 * wy1 : 0.f;

            const bf16x4 g00 = *(const bf16x4*)(vb + (long)(cy0 * Wl + cx0) * 32);
            const bf16x4 g10 = *(const bf16x4*)(vb + (long)(cy0 * Wl + cx1) * 32);
            const bf16x4 g01 = *(const bf16x4*)(vb + (long)(cy1 * Wl + cx0) * 32);
            const bf16x4 g11 = *(const bf16x4*)(vb + (long)(cy1 * Wl + cx1) * 32);

            const float awv = a[lvl * 4 + p] * inv;
            #pragma unroll
            for (int e = 0; e < 4; ++e) {
                float sv = w00 * bf2f(g00[e]) + w10 * bf2f(g10[e])
                         + w01 * bf2f(g01[e]) + w11 * bf2f(g11[e]);
                (&acc.x)[e] += awv * sv;
            }
        }
    }
    bf16x4 ob;
    ob[0] = f2bf(acc.x); ob[1] = f2bf(acc.y);
    ob[2] = f2bf(acc.z); ob[3] = f2bf(acc.w);
    ATTb[row * 64 + h * 8 + d4] = ob;
}

// ---------------------------------------------------------------------------
extern "C" void kernel_launch(void* const* d_in, const int* in_sizes, int n_in,
                              void* d_out, int out_size, void* d_ws, size_t ws_size,
                              hipStream_t stream)
{
    const float* src = (const float*)d_in[0];
    const float* pos = (const float*)d_in[1];
    const float* vr  = (const float*)d_in[2];
    const float* Wv_   = (const float*)d_in[3];
    const float* bv_   = (const float*)d_in[4];
    const float* Woff_ = (const float*)d_in[5];
    const float* boff_ = (const float*)d_in[6];
    const float* Wa_   = (const float*)d_in[7];
    const float* ba_   = (const float*)d_in[8];
    const float* Wo_   = (const float*)d_in[9];
    const float* bo_   = (const float*)d_in[10];
    const float* g1_   = (const float*)d_in[11];
    const float* be1_  = (const float*)d_in[12];
    const float* Wl1_  = (const float*)d_in[13];
    const float* bl1_  = (const float*)d_in[14];
    const float* Wl2_  = (const float*)d_in[15];
    const float* bl2_  = (const float*)d_in[16];
    const float* g2_   = (const float*)d_in[17];
    const float* be2_  = (const float*)d_in[18];

    const long SZ = (long)MROWS * DM;        // 2,785,280 elements
    float* ws = (float*)d_ws;
    float* OFF  = ws;                         // f32 M x 256
    float* AW   = OFF + SZ;                   // f32 M x 128
    short* Vb   = (short*)(AW + (long)MROWS * 128);  // bf16 (NB*NH, LEN, 32)
    short* curb = Vb   + SZ;                  // bf16 M x 256 (trunk)
    short* qb   = curb + SZ;                  // bf16 M x 256 (trunk + pos)
    short* ATTb = qb   + SZ;                  // bf16 M x 256
    short* XAb  = ATTb + SZ;                  // bf16 M x 256 (LN1 out)
    short* FFNb = XAb  + SZ;                  // bf16 M x 1024
    short* Wt   = FFNb + (long)MROWS * DFFN;  // 2 x 753664 bf16 weights
    float* PART = (float*)(Wt + 2L * 753664); // f32 2 x M x 256 partials

    const dim3 blk(256);
    const int GYM = MROWS / 128;              // 85
    const int GLN = MROWS / 32;               // 340

    hipLaunchKernelGGL(prep_all, dim3(1472 + SZ / 4 / 256), blk, 0, stream,
                       Wv_, Woff_, Wa_, Wo_, Wl1_, Wl2_, Wt,
                       (const float4*)src, (const float4*)pos,
                       (bf16x4*)curb, (bf16x4*)qb);

    for (int l = 0; l < 2; ++l) {
        const short* Wbase = Wt + (long)l * 753664;
        const float* bv   = bv_   + (long)l * DM;
        const float* boff = boff_ + (long)l * 256;
        const float* ba   = ba_   + (long)l * 128;
        const float* bo   = bo_   + (long)l * DM;
        const float* g1   = g1_   + (long)l * DM;
        const float* be1  = be1_  + (long)l * DM;
        const float* bl1  = bl1_  + (long)l * DFFN;
        const float* bl2  = bl2_  + (long)l * DM;
        const float* g2   = g2_   + (long)l * DM;
        const float* be2  = be2_  + (long)l * DM;

        // [Vb | OFF | AW] = [curb | qb] @ [Wv|Woff|Wa]   (BN=128, 5x85)
        hipLaunchKernelGGL(gemm_qkv128, dim3(5, GYM), blk, 0, stream,
                           curb, qb, Wbase, bv, boff, ba, Vb, OFF, AW);
        hipLaunchKernelGGL(deform_attn_v3, dim3(MROWS / 4), blk, 0, stream,
                           Vb, OFF, AW, vr, (bf16x4*)ATTb);
        // XAb = bf16( LN(curb + ATT@Wo + bo) )
        hipLaunchKernelGGL((gemm_ln<256>), dim3(GLN), blk, 0, stream,
                           ATTb, Wbase + 163840, bo, curb, g1, be1,
                           XAb, (short*)nullptr, (float*)nullptr,
                           (const float*)nullptr);
        // FFNb = relu(XAb @ Wl1 + bl1)  bf16 out  (BN=128, 8x85)
        hipLaunchKernelGGL((gemm128v3<1, 1, 256>), dim3(8, GYM), blk, 0, stream,
                           XAb, Wbase + 229376, bl1, (float*)nullptr, FFNb, 1024);
        // ln2 split-K partials via M128 pipeline (4 x 85), then finisher
        hipLaunchKernelGGL(ln2_part128, dim3(4, GYM), blk, 0, stream,
                           FFNb, Wbase + 491520, PART);
        if (l == 0) {
            hipLaunchKernelGGL(ln2_fin_k, dim3(GLN), blk, 0, stream,
                               PART, XAb, bl2, g2, be2,
                               curb, qb, (float*)nullptr, pos);
        } else {
            hipLaunchKernelGGL(ln2_fin_k, dim3(GLN), blk, 0, stream,
                               PART, XAb, bl2, g2, be2,
                               (short*)nullptr, (short*)nullptr,
                               (float*)d_out, (const float*)nullptr);
        }
    }
}